// Round 14
// baseline (26.194 us; speedup 1.0000x reference)
//
#include <hip/hip_runtime.h>
#include <float.h>

// ROI max-pool via sliding-4-max pyramid. Clean two-kernel structure
// (R13 proved orchestration is not the lever), with:
//  * x-tiled build: block = 4x4 output tile, 7x7 quad LDS halo ->
//    3.06 loads/output (was 7), 512 WGs (was 2048)
//  * zero-idle balanced query: 784 units per XCD class (was 896 + 448 idle),
//    classes cover i-ranges {0,1},{1,2,3},{3,4,5},{5,6} -> 6272 WGs
//   S4x[y][x]  = max fm[y][x..x+3]   (indices clamped at edge)
//   S4y[y][x]  = max fm[y..y+3][x]
//   S4xy[y][x] = max fm[y..y+3][x..x+3]
// Query: bin range (len<=15) covered by <=4 overlapping spans/dim (last at
// e-4; overlap free under fmax); len in {2,3} -> singles.
// Reference semantics:
//   h0=(int)(H*r0); h1=(int)(H*r2); step=(h1-h0)/7
//   bin i<6: [h0+i*step, h0+(i+1)*step); bin 6: [h0+6*step, h1)
//   step==0 -> all valid pixels in bin 6; empty bin -> -FLT_MAX
constexpr int H = 64, W = 64, C = 256, PH = 7, PW = 7;

typedef float f32x4 __attribute__((ext_vector_type(4)));

__device__ __forceinline__ f32x4 vmax4(f32x4 a, f32x4 b) {
    f32x4 r;
    r.x = fmaxf(a.x, b.x); r.y = fmaxf(a.y, b.y);
    r.z = fmaxf(a.z, b.z); r.w = fmaxf(a.w, b.w);
    return r;
}

// ---- x-tiled build: 512 blocks; blockIdx%8 = b*4 + y-quartile ----
// block covers outputs y0..y0+3 x x0..x0+3; halo rows y0..y0+6, quads x0..x0+6
__global__ __launch_bounds__(256) void build_tables(
    const float* __restrict__ fm, float* __restrict__ s4x,
    float* __restrict__ s4y, float* __restrict__ s4xy)
{
    __shared__ f32x4 lfm[7][7][64];                  // [row][colquad][lane] 49 KB

    const int lane = threadIdx.x & 63;
    const int wave = __builtin_amdgcn_readfirstlane(threadIdx.x >> 6); // 0..3

    const int x8 = blockIdx.x & 7;
    const int z  = blockIdx.x >> 3;                  // 0..63
    const int b  = x8 >> 2;                          // batch
    const int quart = x8 & 3;                        // y-quartile (XCD match)
    const int y0 = quart * 16 + ((z >> 4) << 2);     // 4-row band
    const int x0 = (z & 15) << 2;                    // 4-col tile

    const float* fmb = fm + (size_t)b * H * W * C + (size_t)lane * 4;

    // stage 7x7 halo (row, colquad), both clamped at 63 (== table edge rule)
    for (int q = wave; q < 49; q += 4) {
        const int row = q / 7, col = q % 7;
        const int y  = min(y0 + row, H - 1);
        const int xq = min(x0 + col, W - 1);
        lfm[row][col][lane] = *(const f32x4*)(fmb + ((size_t)y * W + xq) * C);
    }
    __syncthreads();

    // wave w produces output row y0+w, cols x0..x0+3
    f32x4 rowv[7], colm[7];
    #pragma unroll
    for (int c = 0; c < 7; ++c) {
        rowv[c] = lfm[wave][c][lane];
        colm[c] = vmax4(vmax4(rowv[c],            lfm[wave + 1][c][lane]),
                        vmax4(lfm[wave + 2][c][lane], lfm[wave + 3][c][lane]));
    }

    const int y = y0 + wave;                         // <= 63 always
    #pragma unroll
    for (int ox = 0; ox < 4; ++ox) {
        const f32x4 sx  = vmax4(vmax4(rowv[ox], rowv[ox + 1]),
                                vmax4(rowv[ox + 2], rowv[ox + 3]));
        const f32x4 sy  = colm[ox];
        const f32x4 sxy = vmax4(vmax4(colm[ox], colm[ox + 1]),
                                vmax4(colm[ox + 2], colm[ox + 3]));
        const size_t o = ((size_t)(b * H + y) * W + (x0 + ox)) * C + (size_t)lane * 4;
        *(f32x4*)(s4x  + o) = sx;
        *(f32x4*)(s4y  + o) = sy;
        *(f32x4*)(s4xy + o) = sxy;
    }
}

// ---------- verified bin bounds (reference semantics) ----------
__device__ __forceinline__ void bin_bounds(
    const float* __restrict__ rois, int b, int R, int r, int i, int j,
    int& ys, int& ye, int& xs, int& xe)
{
    const float* roi = rois + ((size_t)b * R + r) * 4;
    int h0 = (int)((float)H * roi[0]);               // trunc == astype(int32)
    int w0 = (int)((float)W * roi[1]);
    int h1 = (int)((float)H * roi[2]);
    int w1 = (int)((float)W * roi[3]);
    int hs = (h1 - h0) / PH;
    int ws = (w1 - w0) / PW;

    if (hs > 0) { ys = h0 + i * hs; ye = (i < PH - 1) ? (ys + hs) : h1; }
    else        { ys = h0;          ye = (i == PH - 1) ? h1 : h0; }
    if (ws > 0) { xs = w0 + j * ws; xe = (j < PW - 1) ? (xs + ws) : w1; }
    else        { xs = w0;          xe = (j == PW - 1) ? w1 : w0; }
    ys = __builtin_amdgcn_readfirstlane(max(ys, 0));
    ye = __builtin_amdgcn_readfirstlane(min(ye, H));
    xs = __builtin_amdgcn_readfirstlane(max(xs, 0));
    xe = __builtin_amdgcn_readfirstlane(min(xe, W));
}

// ---------- verified gather (R8/R10 span logic) ----------
__device__ __forceinline__ f32x4 gather_bin(
    int b, int lane, int ys, int ye, int xs, int xe, bool use_tables,
    const float* __restrict__ fm, const float* __restrict__ s4x,
    const float* __restrict__ s4y, const float* __restrict__ s4xy)
{
    const int hl = ye - ys, wl = xe - xs;
    const f32x4 NEG = {-FLT_MAX, -FLT_MAX, -FLT_MAX, -FLT_MAX};
    f32x4 a0 = NEG, a1 = NEG, a2 = NEG, a3 = NEG;

    if (hl > 0 && wl > 0) {
        if (use_tables) {
            const bool y4 = hl >= 4, x4 = wl >= 4;   // len<=15 -> <=4 spans/dim
            const int ny = y4 ? (hl + 3) >> 2 : hl;
            const int nx = x4 ? (wl + 3) >> 2 : wl;
            const int ystep = y4 ? 4 : 1, xstep = x4 ? 4 : 1;
            const int ycl = y4 ? ye - 4 : ye - 1;
            const int xcl = x4 ? xe - 4 : xe - 1;
            const float* tb = y4 ? (x4 ? s4xy : s4y) : (x4 ? s4x : fm);
            const float* tbb = tb + (size_t)b * H * W * C + lane * 4;

            const int xo0 = min(xs,             xcl) * C;
            const int xo1 = min(xs + xstep,     xcl) * C;
            const int xo2 = min(xs + 2 * xstep, xcl) * C;
            const int xo3 = min(xs + 3 * xstep, xcl) * C;

            #pragma unroll
            for (int ky = 0; ky < 4; ++ky) {
                if (ky < ny) {                       // wave-uniform guard
                    const int y = min(ys + ystep * ky, ycl);
                    const float* rowp = tbb + (size_t)y * (W * C);
                    a0 = vmax4(a0, *(const f32x4*)(rowp + xo0));
                    if (nx > 1) a1 = vmax4(a1, *(const f32x4*)(rowp + xo1));
                    if (nx > 2) a2 = vmax4(a2, *(const f32x4*)(rowp + xo2));
                    if (nx > 3) a3 = vmax4(a3, *(const f32x4*)(rowp + xo3));
                }
            }
        } else {                                     // direct from fm
            const float* fmb2 = fm + (size_t)b * (H * W * C) + lane * 4;
            for (int y = ys; y < ye; y += 2) {
                const int yb = min(y + 1, ye - 1);
                const int ro0 = y  * (W * C);
                const int ro1 = yb * (W * C);
                for (int x = xs; x < xe; x += 2) {
                    const int xb = min(x + 1, xe - 1);
                    a0 = vmax4(a0, *(const f32x4*)(fmb2 + ro0 + x  * C));
                    a1 = vmax4(a1, *(const f32x4*)(fmb2 + ro0 + xb * C));
                    a2 = vmax4(a2, *(const f32x4*)(fmb2 + ro1 + x  * C));
                    a3 = vmax4(a3, *(const f32x4*)(fmb2 + ro1 + xb * C));
                }
            }
        }
    }
    return vmax4(vmax4(a0, a1), vmax4(a2, a3));
}

// ---- query: 6272 blocks, zero idle; blockIdx%8 = b*4 + class ----
// class c owns units t = c*784 + n (n in [0,784)); i = t/448, id = (t%448)*4+wave
// class i-ranges: c0:{0,1} c1:{1,2,3} c2:{3,4,5} c3:{5,6} (contiguous rows/XCD)
__global__ __launch_bounds__(256) void roi_pool_q(
    const float* __restrict__ fm, const float* __restrict__ rois,
    const float* __restrict__ s4x, const float* __restrict__ s4y,
    const float* __restrict__ s4xy, float* __restrict__ out, int R)
{
    const int lane = threadIdx.x & 63;
    const int wave = __builtin_amdgcn_readfirstlane(threadIdx.x >> 6);

    const int x8 = blockIdx.x & 7;                   // XCD slot
    const int n  = blockIdx.x >> 3;                  // [0, 784)
    const int b  = x8 >> 2;                          // batch
    const int c  = x8 & 3;                           // class

    const int t  = c * 784 + n;                      // [0, 3136)
    const int i  = t / 448;                          // bin row 0..6
    const int m  = t - 448 * i;
    const int id = m * 4 + wave;                     // [0, 1792)
    const int r  = id / 7;                           // roi
    const int j  = id - 7 * r;                       // col bin

    int ys, ye, xs, xe;
    bin_bounds(rois, b, R, r, i, j, ys, ye, xs, xe);
    const f32x4 acc = gather_bin(b, lane, ys, ye, xs, xe, true,
                                 fm, s4x, s4y, s4xy);
    size_t o = ((((size_t)b * R + r) * PH + i) * PW + j) * C + (size_t)lane * 4;
    __builtin_nontemporal_store(acc, reinterpret_cast<f32x4*>(out + o));
}

// ---- verified direct fallback (R5 kernel) if ws too small ----
__global__ __launch_bounds__(256) void roi_pool_direct(
    const float* __restrict__ fm, const float* __restrict__ rois,
    float* __restrict__ out, int R)
{
    const int lane = threadIdx.x & 63;
    const int wave = __builtin_amdgcn_readfirstlane(threadIdx.x >> 6);
    const int b = blockIdx.x & 1;
    int m = (blockIdx.x >> 1) * 4 + wave;
    int j = m % PW; m /= PW;
    int i = m % PH; m /= PH;
    int r = m;

    int ys, ye, xs, xe;
    bin_bounds(rois, b, R, r, i, j, ys, ye, xs, xe);
    const f32x4 acc = gather_bin(b, lane, ys, ye, xs, xe, false,
                                 fm, nullptr, nullptr, nullptr);
    size_t o = ((((size_t)b * R + r) * PH + i) * PW + j) * C + (size_t)lane * 4;
    __builtin_nontemporal_store(acc, reinterpret_cast<f32x4*>(out + o));
}

extern "C" void kernel_launch(void* const* d_in, const int* in_sizes, int n_in,
                              void* d_out, int out_size, void* d_ws, size_t ws_size,
                              hipStream_t stream) {
    const float* fm   = (const float*)d_in[0];
    const float* rois = (const float*)d_in[1];
    float* out = (float*)d_out;

    const int B = in_sizes[0] / (H * W * C);        // = 2
    const int R = in_sizes[1] / (B * 4);            // = 256

    const size_t tbl = (size_t)B * H * W * C;       // floats per table
    const size_t need = 3 * tbl * sizeof(float);    // 24 MB for B=2

    if (B == 2 && R == 256 && ws_size >= need) {
        float* s4x  = (float*)d_ws;
        float* s4y  = s4x + tbl;
        float* s4xy = s4y + tbl;
        build_tables<<<512,  256, 0, stream>>>(fm, s4x, s4y, s4xy);
        roi_pool_q  <<<6272, 256, 0, stream>>>(fm, rois, s4x, s4y, s4xy, out, R);
    } else {
        const int qblocks = B * (R * PH * PW / 4);
        roi_pool_direct<<<qblocks, 256, 0, stream>>>(fm, rois, out, R);
    }
}

// Round 15
// 24.079 us; speedup vs baseline: 1.0878x; 1.0878x over previous
//
#include <hip/hip_runtime.h>
#include <float.h>

// ROI max-pool via sliding-4-max pyramid — the R10-verified configuration
// (best measured: 24.29us; beat fused-barrier variants and the x-tiled /
// balanced "improvements").
//   S4x[y][x]  = max fm[y][x..x+3]   (indices clamped at edge)
//   S4y[y][x]  = max fm[y..y+3][x]
//   S4xy[y][x] = max fm[y..y+3][x..x+3]
// Build: 2048 blocks; blockIdx%8 = b*4 + y-quartile (XCD-pinned so the
// quartile's table slice lands in the L2 that will query it).
// Query: 7168 blocks; blockIdx%8 = b*4 + i-group ({0,1},{2,3},{4,5},{6});
// each XCD reads only its ~2.5-3.5 MB table slice -> L2-resident.
// Bin range (len<=15) covered by <=4 overlapping 4-spans/dim (last at e-4;
// overlap free under fmax); len in {2,3} -> singles.
// Reference semantics:
//   h0=(int)(H*r0); h1=(int)(H*r2); step=(h1-h0)/7
//   bin i<6: [h0+i*step, h0+(i+1)*step); bin 6: [h0+6*step, h1)
//   step==0 -> all valid pixels in bin 6; empty bin -> -FLT_MAX
constexpr int H = 64, W = 64, C = 256, PH = 7, PW = 7;

typedef float f32x4 __attribute__((ext_vector_type(4)));

__device__ __forceinline__ f32x4 vmax4(f32x4 a, f32x4 b) {
    f32x4 r;
    r.x = fmaxf(a.x, b.x); r.y = fmaxf(a.y, b.y);
    r.z = fmaxf(a.z, b.z); r.w = fmaxf(a.w, b.w);
    return r;
}

// ---- fused build: 2048 blocks; blockIdx%8 = b*4 + y-quartile ----
__global__ __launch_bounds__(256) void build_tables(
    const float* __restrict__ fm, float* __restrict__ s4x,
    float* __restrict__ s4y, float* __restrict__ s4xy)
{
    __shared__ f32x4 lds_fm[7][64];    // fm[y0+k][x] channel quads
    __shared__ f32x4 lds_sx[7][64];    // s4x[y0+k][x]

    const int lane = threadIdx.x & 63;
    const int wave = __builtin_amdgcn_readfirstlane(threadIdx.x >> 6); // 0..3

    const int x8 = blockIdx.x & 7;
    const int z  = blockIdx.x >> 3;                  // 0..255
    const int b  = x8 >> 2;                          // batch
    const int quart = x8 & 3;                        // y-quartile -> query XCD
    const int x  = z & (W - 1);
    const int y0 = quart * 16 + ((z >> 6) << 2);     // 4-row band

    const int x1 = min(x + 1, W - 1), x2 = min(x + 2, W - 1), x3 = min(x + 3, W - 1);
    const float* fmb = fm + (size_t)b * H * W * C + (size_t)lane * 4;

    // wave w owns halo slots {w} and (w<3 ? {4+w} : {})
    #pragma unroll
    for (int s = 0; s < 2; ++s) {
        const int slot = wave + 4 * s;
        if (slot < 7) {
            const int y = min(y0 + slot, H - 1);     // clamp == table edge rule
            const float* row = fmb + (size_t)y * W * C;
            f32x4 v0 = *(const f32x4*)(row + (size_t)x  * C);
            f32x4 v1 = *(const f32x4*)(row + (size_t)x1 * C);
            f32x4 v2 = *(const f32x4*)(row + (size_t)x2 * C);
            f32x4 v3 = *(const f32x4*)(row + (size_t)x3 * C);
            lds_fm[slot][lane] = v0;
            lds_sx[slot][lane] = vmax4(vmax4(v0, v1), vmax4(v2, v3));
        }
    }
    __syncthreads();

    const int y = y0 + wave;
    const f32x4 sx = lds_sx[wave][lane];
    const f32x4 sy = vmax4(vmax4(lds_fm[wave][lane],     lds_fm[wave + 1][lane]),
                           vmax4(lds_fm[wave + 2][lane], lds_fm[wave + 3][lane]));
    const f32x4 sxy = vmax4(vmax4(lds_sx[wave][lane],     lds_sx[wave + 1][lane]),
                            vmax4(lds_sx[wave + 2][lane], lds_sx[wave + 3][lane]));

    const size_t o = ((size_t)(b * H + y) * W + x) * C + (size_t)lane * 4;
    *(f32x4*)(s4x  + o) = sx;
    *(f32x4*)(s4y  + o) = sy;
    *(f32x4*)(s4xy + o) = sxy;
}

// ---- query: 7168 blocks; blockIdx%8 = b*4 + i-group ----
__global__ __launch_bounds__(256) void roi_pool_q(
    const float* __restrict__ fm, const float* __restrict__ rois,
    const float* __restrict__ s4x, const float* __restrict__ s4y,
    const float* __restrict__ s4xy, float* __restrict__ out, int R)
{
    const int lane = threadIdx.x & 63;
    const int wave = __builtin_amdgcn_readfirstlane(threadIdx.x >> 6);

    const int x8 = blockIdx.x & 7;                   // XCD slot
    const int n  = blockIdx.x >> 3;                  // [0, 896)
    const int b  = x8 >> 2;                          // batch
    const int g  = x8 & 3;                           // i-group {0,1},{2,3},{4,5},{6}

    int i, id;
    if (g < 3) {
        i  = 2 * g + (n & 1);
        id = (n >> 1) * 4 + wave;                    // [0, 1792)
    } else {
        if (n >= 448) return;                        // pad blocks: idle
        i  = 6;
        id = n * 4 + wave;
    }
    const int r = id / 7;                            // roi
    const int j = id - 7 * r;                        // col bin

    const float* roi = rois + ((size_t)b * R + r) * 4;
    int h0 = (int)((float)H * roi[0]);               // trunc == astype(int32)
    int w0 = (int)((float)W * roi[1]);
    int h1 = (int)((float)H * roi[2]);
    int w1 = (int)((float)W * roi[3]);
    int hs = (h1 - h0) / PH;
    int ws = (w1 - w0) / PW;

    int ys, ye, xs, xe;
    if (hs > 0) { ys = h0 + i * hs; ye = (i < PH - 1) ? (ys + hs) : h1; }
    else        { ys = h0;          ye = (i == PH - 1) ? h1 : h0; }
    if (ws > 0) { xs = w0 + j * ws; xe = (j < PW - 1) ? (xs + ws) : w1; }
    else        { xs = w0;          xe = (j == PW - 1) ? w1 : w0; }
    ys = __builtin_amdgcn_readfirstlane(max(ys, 0));
    ye = __builtin_amdgcn_readfirstlane(min(ye, H));
    xs = __builtin_amdgcn_readfirstlane(max(xs, 0));
    xe = __builtin_amdgcn_readfirstlane(min(xe, W));

    const int hl = ye - ys, wl = xe - xs;
    const f32x4 NEG = {-FLT_MAX, -FLT_MAX, -FLT_MAX, -FLT_MAX};
    f32x4 a0 = NEG, a1 = NEG, a2 = NEG, a3 = NEG;   // per-kx-slot accumulators

    if (hl > 0 && wl > 0) {
        // bin length <= 15 always -> <=4 spans per dim
        const bool y4 = hl >= 4, x4 = wl >= 4;
        const int ny = y4 ? (hl + 3) >> 2 : hl;     // <= 4
        const int nx = x4 ? (wl + 3) >> 2 : wl;     // <= 4
        const int ystep = y4 ? 4 : 1, xstep = x4 ? 4 : 1;
        const int ycl = y4 ? ye - 4 : ye - 1;
        const int xcl = x4 ? xe - 4 : xe - 1;
        const float* tb = y4 ? (x4 ? s4xy : s4y) : (x4 ? s4x : fm);
        const float* tbb = tb + (size_t)b * H * W * C + lane * 4;

        // x-span byte offsets (uniform)
        const int xo0 = min(xs,             xcl) * C;
        const int xo1 = min(xs + xstep,     xcl) * C;
        const int xo2 = min(xs + 2 * xstep, xcl) * C;
        const int xo3 = min(xs + 3 * xstep, xcl) * C;

        #pragma unroll
        for (int ky = 0; ky < 4; ++ky) {
            if (ky < ny) {                           // wave-uniform guard
                const int y = min(ys + ystep * ky, ycl);
                const float* rowp = tbb + (size_t)y * (W * C);
                a0 = vmax4(a0, *(const f32x4*)(rowp + xo0));
                if (nx > 1) a1 = vmax4(a1, *(const f32x4*)(rowp + xo1));
                if (nx > 2) a2 = vmax4(a2, *(const f32x4*)(rowp + xo2));
                if (nx > 3) a3 = vmax4(a3, *(const f32x4*)(rowp + xo3));
            }
        }
    }
    const f32x4 acc = vmax4(vmax4(a0, a1), vmax4(a2, a3));

    size_t o = ((((size_t)b * R + r) * PH + i) * PW + j) * C + (size_t)lane * 4;
    __builtin_nontemporal_store(acc, reinterpret_cast<f32x4*>(out + o));
}

// ---- verified fallback (R5 kernel) if ws too small ----
__global__ __launch_bounds__(256) void roi_pool_direct(
    const float* __restrict__ fm, const float* __restrict__ rois,
    float* __restrict__ out, int R)
{
    const int lane = threadIdx.x & 63;
    const int wave = __builtin_amdgcn_readfirstlane(threadIdx.x >> 6);
    const int b = blockIdx.x & 1;
    int m = (blockIdx.x >> 1) * 4 + wave;
    int j = m % PW; m /= PW;
    int i = m % PH; m /= PH;
    int r = m;

    const float* roi = rois + ((size_t)b * R + r) * 4;
    int h0 = (int)((float)H * roi[0]);
    int w0 = (int)((float)W * roi[1]);
    int h1 = (int)((float)H * roi[2]);
    int w1 = (int)((float)W * roi[3]);
    int hs = (h1 - h0) / PH;
    int ws = (w1 - w0) / PW;

    int ys, ye, xs, xe;
    if (hs > 0) { ys = h0 + i * hs; ye = (i < PH - 1) ? (ys + hs) : h1; }
    else        { ys = h0;          ye = (i == PH - 1) ? h1 : h0; }
    if (ws > 0) { xs = w0 + j * ws; xe = (j < PW - 1) ? (xs + ws) : w1; }
    else        { xs = w0;          xe = (j == PW - 1) ? w1 : w0; }
    ys = __builtin_amdgcn_readfirstlane(max(ys, 0));
    ye = __builtin_amdgcn_readfirstlane(min(ye, H));
    xs = __builtin_amdgcn_readfirstlane(max(xs, 0));
    xe = __builtin_amdgcn_readfirstlane(min(xe, W));

    const f32x4 NEG = {-FLT_MAX, -FLT_MAX, -FLT_MAX, -FLT_MAX};
    f32x4 a0 = NEG, a1 = NEG, a2 = NEG, a3 = NEG;
    const float* fmb = fm + (size_t)b * (H * W * C);
    const int lo = lane * 4;

    for (int y = ys; y < ye; y += 2) {
        const int y1 = min(y + 1, ye - 1);
        const int ro0 = y  * (W * C);
        const int ro1 = y1 * (W * C);
        for (int x = xs; x < xe; x += 2) {
            const int x1 = min(x + 1, xe - 1);
            a0 = vmax4(a0, *(const f32x4*)(fmb + ro0 + x  * C + lo));
            a1 = vmax4(a1, *(const f32x4*)(fmb + ro0 + x1 * C + lo));
            a2 = vmax4(a2, *(const f32x4*)(fmb + ro1 + x  * C + lo));
            a3 = vmax4(a3, *(const f32x4*)(fmb + ro1 + x1 * C + lo));
        }
    }
    f32x4 acc = vmax4(vmax4(a0, a1), vmax4(a2, a3));
    size_t o = ((((size_t)b * R + r) * PH + i) * PW + j) * C + (size_t)lo;
    __builtin_nontemporal_store(acc, reinterpret_cast<f32x4*>(out + o));
}

extern "C" void kernel_launch(void* const* d_in, const int* in_sizes, int n_in,
                              void* d_out, int out_size, void* d_ws, size_t ws_size,
                              hipStream_t stream) {
    const float* fm   = (const float*)d_in[0];
    const float* rois = (const float*)d_in[1];
    float* out = (float*)d_out;

    const int B = in_sizes[0] / (H * W * C);        // = 2
    const int R = in_sizes[1] / (B * 4);            // = 256

    const size_t tbl = (size_t)B * H * W * C;       // floats per table
    const size_t need = 3 * tbl * sizeof(float);    // 24 MB for B=2

    if (B == 2 && R == 256 && ws_size >= need) {
        float* s4x  = (float*)d_ws;
        float* s4y  = s4x + tbl;
        float* s4xy = s4y + tbl;
        build_tables<<<2048, 256, 0, stream>>>(fm, s4x, s4y, s4xy);
        roi_pool_q  <<<7168, 256, 0, stream>>>(fm, rois, s4x, s4y, s4xy, out, R);
    } else {
        const int qblocks = B * (R * PH * PW / 4);
        roi_pool_direct<<<qblocks, 256, 0, stream>>>(fm, rois, out, R);
    }
}